// Round 1
// 978.489 us; speedup vs baseline: 1.2152x; 1.2152x over previous
//
#include <hip/hip_runtime.h>

// R5: single-wave-per-group design. Block = 64 thr = 1 wave owning ALL 64
// output channels (4 M-tiles) of layers 1&2 for its 16-batch group.
// No __syncthreads anywhere: inter-layer activation transpose goes through
// per-block LDS within the single wave (compiler-ordered via lgkmcnt only).
// Rationale: R4 (2-wave channel split) paid 8 barriers/timestep (wave skew +
// LDS round-trip fully exposed, 1 wave/SIMD so no hiding) while replicating
// the per-batch scalar section in both waves. Single wave: same per-wave
// scalar VALU (replication across q-quads is cycle-free), +sigmoid second
// half, zero barriers, per-CU VALU halves.
// sigma-folding retained: tanh(a)=1-2*sigma(2a), -2 and 2*log2(e) folded
// into weights/biases so each activation is rcp(1+exp2(c)). Numerics are
// bit-identical to R4 (same tiles, same accumulate order, same rounding).

typedef _Float16 h2_t __attribute__((ext_vector_type(2)));
typedef _Float16 h8_t __attribute__((ext_vector_type(8)));
typedef __fp16  pk2_t __attribute__((ext_vector_type(2)));
typedef float f4_t __attribute__((ext_vector_type(4)));

union H8 { h8_t v; h2_t h[4]; int i[4]; int4 i4; };
union H2I { h2_t h; pk2_t p; int i; float _f; };

#define DEVI __device__ __forceinline__

DEVI float rcp_f(float x) { return __builtin_amdgcn_rcpf(x); }
#if __has_builtin(__builtin_amdgcn_exp2f)
DEVI float exp2_f(float x) { return __builtin_amdgcn_exp2f(x); }
#else
DEVI float exp2_f(float x) { return __expf(x * 0.69314718056f); }
#endif
DEVI int pkrtz_i(float a, float b) { H2I u; u.p = __builtin_amdgcn_cvt_pkrtz(a, b); return u.i; }
DEVI h2_t pkrtz(float a, float b)  { H2I u; u.p = __builtin_amdgcn_cvt_pkrtz(a, b); return u.h; }
DEVI int bperm(int addr, int src) { return __builtin_amdgcn_ds_bpermute(addr, src); }
DEVI int h2i(h2_t h) { H2I u; u.h = h; return u.i; }

DEVI f4_t mfma16(h8_t a, h8_t b, f4_t c) {
    return __builtin_amdgcn_mfma_f32_16x16x32_f16(a, b, c, 0, 0, 0);
}

DEVI int qsel(int q, int a, int b, int c, int d) {
    int x = (q == 0) ? a : b;
    int y = (q == 2) ? c : d;
    return (q < 2) ? x : y;
}

// grey-box CSTR+flash RHS, scaled coords, per-lane (batch = lane&15)
DEVI void fg_eval(const float x[8], float F, float D, float kfg[8]) {
    float Hr  = fmaf(x[0], 0.3f, 0.7f);
    float CAr = fmaf(x[1], 0.2f, 0.5f);
    float CBr = fmaf(x[2], 0.2f, 0.5f);
    float Tr  = fmaf(x[3], 5.0f, 310.0f);
    float Hb  = fmaf(x[4], 0.3f, 0.7f);
    float CAb = fmaf(x[5], 0.2f, 0.5f);
    float CBb = fmaf(x[6], 0.2f, 0.5f);
    float Tb  = fmaf(x[7], 5.0f, 310.0f);

    float aA = 3.5f * CAb, aB = 1.1f * CBb;
    float rden = rcp_f(aA + aB);
    float CAd = aA * rden, CBd = aB * rden;
    float Fr = __builtin_amdgcn_sqrtf(Hr);
    float Fb = __builtin_amdgcn_sqrtf(Hb);
    float rTr = rcp_f(Tr);
    float k1v = 20000.0f * __expf(-3000.0f * rTr);
    float r1 = k1v * CAr;
    float rHr = rcp_f(Hr), rHb = rcp_f(Hb);

    float dHr  = F + D - Fr;
    float dCAr = (F * (1.0f - CAr) + D * (CAd - CAr)) * rHr - r1;
    float dCBr = (D * (CBd - CBr) - F * CBr) * rHr + r1;
    float dTr  = (F * (320.0f - Tr) + D * (310.0f - Tr)) * rHr
               - (40.0f / 3.0f) * rHr + (2.0f / 3.0f) * r1;
    float dHb  = Fr - Fb - D;
    float dCAb = (Fr * (CAr - CAb) + D * (CAb - CAd)) * rHb;
    float dCBb = (Fr * (CBr - CBb) + D * (CBb - CBd)) * rHb;
    float dTb  = Fr * (Tr - Tb) * rHb + (40.0f / 3.0f) * rHb;

    kfg[0] = dHr  * (10.0f / 3.0f);
    kfg[1] = dCAr * 5.0f;
    kfg[2] = dCBr * 5.0f;
    kfg[3] = dTr  * 0.2f;
    kfg[4] = dHb  * (10.0f / 3.0f);
    kfg[5] = dCAb * 5.0f;
    kfg[6] = dCBb * 5.0f;
    kfg[7] = dTb  * 0.2f;
}

struct Weights {
    h8_t a1[4][2], a2[4][2], a3[2];
    f4_t b1f[4], b2f[4], b3f;
};

// sigma transition through LDS: 4 C-tiles -> sigma(f16 pairs) -> LDS
// row[batch] -> read back full-K B-frags. Single wave: no barrier; the
// compiler orders the same-buffer write->read with lgkmcnt.
DEVI void transition_lds(const f4_t acc[4], int* __restrict__ buf,
                         int wrbase, int rdbase, H8& g0, H8& g1) {
#pragma unroll
    for (int ct = 0; ct < 4; ++ct) {
        float s0 = rcp_f(1.0f + exp2_f(acc[ct][0]));
        float s1 = rcp_f(1.0f + exp2_f(acc[ct][1]));
        float s2 = rcp_f(1.0f + exp2_f(acc[ct][2]));
        float s3 = rcp_f(1.0f + exp2_f(acc[ct][3]));
        int2 pk = { pkrtz_i(s0, s1), pkrtz_i(s2, s3) };
        *(int2*)(buf + wrbase + 8 * ct) = pk;          // ds_write_b64
    }
    g0.i4 = *(const int4*)(buf + rdbase);               // ds_read_b128
    g1.i4 = *(const int4*)(buf + rdbase + 16);
}

// one RK slope: k = fg(x,u) + fnn([x, zvariant, u])
DEVI void eval_stage(const float x[8], const h2_t yv[16], const h2_t up[4],
                     int upair_i, float F, float D, const Weights& W,
                     int q, int wrbase, int rdbase,
                     int* __restrict__ buf0, int* __restrict__ buf1,
                     int iN0, int iN1, float k[8]) {
    // ---- build B1 frags: in = [x(8), ypart(32), upseq(8), u(2), pad] ----
    H8 f0, f1;
#pragma unroll
    for (int i = 0; i < 4; ++i) {
        int pxi = pkrtz_i(x[2 * i], x[2 * i + 1]);
        f0.i[i] = qsel(q, pxi, h2i(yv[i]), h2i(yv[4 + i]), h2i(yv[8 + i]));
        f1.i[i] = qsel(q, h2i(yv[12 + i]), h2i(up[i]),
                       (i == 0) ? upair_i : 0, 0);
    }

    // ---- layer 1 (all 4 M-tiles in this wave) ----
    f4_t a[4];
#pragma unroll
    for (int ct = 0; ct < 4; ++ct) {
        a[ct] = mfma16(W.a1[ct][0], f0.v, W.b1f[ct]);
        a[ct] = mfma16(W.a1[ct][1], f1.v, a[ct]);
    }
    H8 g0, g1;
    transition_lds(a, buf0, wrbase, rdbase, g0, g1);

    // ---- layer 2 ----
#pragma unroll
    for (int ct = 0; ct < 4; ++ct) {
        a[ct] = mfma16(W.a2[ct][0], g0.v, W.b2f[ct]);
        a[ct] = mfma16(W.a2[ct][1], g1.v, a[ct]);
    }
    transition_lds(a, buf1, wrbase, rdbase, g0, g1);

    // ---- layer 3 (full K) ----
    f4_t a3 = mfma16(W.a3[0], g0.v, W.b3f);
    a3 = mfma16(W.a3[1], g1.v, a3);

    // gather nn[c] to every lane (batch = lane&15)
    float nn[8];
#pragma unroll
    for (int c = 0; c < 8; ++c) {
        int idx = (c < 4) ? iN0 : iN1;
        nn[c] = __int_as_float(bperm(idx, __float_as_int(a3[c & 3])));
    }

    float kfg[8];
    fg_eval(x, F, D, kfg);
#pragma unroll
    for (int c = 0; c < 8; ++c) k[c] = kfg[c] + nn[c];
}

__global__ __launch_bounds__(64, 1)
void cstr_mfma1_kernel(const float* __restrict__ useq, const float* __restrict__ xGz0,
                       const float* __restrict__ W1, const float* __restrict__ b1,
                       const float* __restrict__ W2, const float* __restrict__ b2,
                       const float* __restrict__ W3, const float* __restrict__ b3,
                       float* __restrict__ out)
{
    const int lane = threadIdx.x & 63;
    const int m16 = lane & 15, q = lane >> 4;
    const int b0 = blockIdx.x * 16;

    __shared__ int lds[4][16 * 36];         // 4 rotating sigma buffers, 9216 B

    const int wrbase = m16 * 36 + 2 * q;
    const int rdbase = m16 * 36 + 4 * q;
    const int iN0 = m16 << 2;
    const int iN1 = (m16 + 16) << 2;

    const float S1 = 2.0f * 1.4426950408889634f;   // 2*log2(e)

    // ---- preload weights (sigma-folded), all 4 M-tiles ----
    Weights W;
#pragma unroll
    for (int ct = 0; ct < 4; ++ct) {
        const int mt = ct;
#pragma unroll
        for (int kh = 0; kh < 2; ++kh) {
            H8 w1f, w2f;
#pragma unroll
            for (int j = 0; j < 8; ++j) {
                int k = 32 * kh + 8 * q + j;
                int n = 16 * mt + m16;
                float v1 = (k < 50) ? S1 * W1[k * 64 + n] : 0.0f;
                float v2 = -2.0f * S1 * W2[k * 64 + n];
                ((_Float16*)&w1f)[j] = (_Float16)v1;
                ((_Float16*)&w2f)[j] = (_Float16)v2;
            }
            W.a1[ct][kh] = w1f.v;
            W.a2[ct][kh] = w2f.v;
        }
        f4_t bb1, bb2;
#pragma unroll
        for (int r = 0; r < 4; ++r) {
            int ch = 16 * mt + 4 * q + r;
            bb1[r] = S1 * b1[ch];
            float cs = 0.0f;
            for (int j = 0; j < 64; ++j) cs += W2[j * 64 + ch];
            bb2[r] = S1 * (b2[ch] + cs);
        }
        W.b1f[ct] = bb1;
        W.b2f[ct] = bb2;
    }
#pragma unroll
    for (int kh = 0; kh < 2; ++kh) {
        H8 w3f;
#pragma unroll
        for (int j = 0; j < 8; ++j) {
            int k = 32 * kh + 8 * q + j;
            ((_Float16*)&w3f)[j] = (m16 < 8) ? (_Float16)(-2.0f * W3[k * 8 + m16])
                                             : (_Float16)0.0f;
        }
        W.a3[kh] = w3f.v;
    }
    {
        f4_t bb3;
#pragma unroll
        for (int r = 0; r < 4; ++r) {
            int c = 4 * q + r;
            float v = 0.0f;
            if (c < 8) {
                float cs = 0.0f;
                for (int j = 0; j < 64; ++j) cs += W3[j * 8 + c];
                v = b3[c] + cs;
            }
            bb3[r] = v;
        }
        W.b3f = bb3;
    }

    // ---- per-batch state (batch = lane&15; replicated across quads) ----
    const float* xz = xGz0 + (size_t)(b0 + m16) * 48;
    float xg[8];
#pragma unroll
    for (int c = 0; c < 8; ++c) xg[c] = xz[c];
    h2_t p[16];
#pragma unroll
    for (int i = 0; i < 16; ++i) p[i] = pkrtz(xz[8 + 2 * i], xz[9 + 2 * i]);
    h2_t up[4];
#pragma unroll
    for (int i = 0; i < 4; ++i) up[i] = pkrtz(xz[40 + 2 * i], xz[41 + 2 * i]);

    const float* ub = useq + (size_t)(b0 + m16) * 512;
    float* ob = out + (size_t)(b0 + m16) * 2048;

    float kc[8], ks[8], xv[8];

    float2 uu = *(const float2*)(ub);       // u for t=0

#pragma unroll 1
    for (int t = 0; t < 256; ++t) {
        // prefetch next step's u (wraps harmlessly at t=255)
        const float2 uun = *(const float2*)(ub + ((2 * t + 2) & 511));

        const float u0 = uu.x, u1 = uu.y;
        const float F = fmaf(u0, 0.1f, 1.0f);
        const float D = fmaf(u1, 0.05f, 0.5f);
        const int upair_i = pkrtz_i(u0, u1);

        // ycat pairs = [ypseq(16 pairs), xG(4 pairs)]
        h2_t pc[20];
#pragma unroll
        for (int i = 0; i < 16; ++i) pc[i] = p[i];
#pragma unroll
        for (int i = 0; i < 4; ++i) pc[16 + i] = pkrtz(xg[2 * i], xg[2 * i + 1]);
        h2_t pi[16], ps[16];
        const h2_t half2c = { (_Float16)0.5f, (_Float16)0.5f };
#pragma unroll
        for (int i = 0; i < 16; ++i) {
            pi[i] = (pc[i] + pc[i + 4]) * half2c;
            ps[i] = pc[i + 4];
        }

        // ---- RK4 (LDS buffers rotate per transition; no barriers) ----
        eval_stage(xg, p,  up, upair_i, F, D, W, q, wrbase, rdbase,
                   lds[0], lds[1], iN0, iN1, kc);
#pragma unroll
        for (int c = 0; c < 8; ++c) { ks[c] = kc[c]; xv[c] = fmaf(0.005f, kc[c], xg[c]); }
        eval_stage(xv, pi, up, upair_i, F, D, W, q, wrbase, rdbase,
                   lds[2], lds[3], iN0, iN1, kc);
#pragma unroll
        for (int c = 0; c < 8; ++c) { ks[c] = fmaf(2.0f, kc[c], ks[c]); xv[c] = fmaf(0.005f, kc[c], xg[c]); }
        eval_stage(xv, pi, up, upair_i, F, D, W, q, wrbase, rdbase,
                   lds[0], lds[1], iN0, iN1, kc);
#pragma unroll
        for (int c = 0; c < 8; ++c) { ks[c] = fmaf(2.0f, kc[c], ks[c]); xv[c] = fmaf(0.01f, kc[c], xg[c]); }
        eval_stage(xv, ps, up, upair_i, F, D, W, q, wrbase, rdbase,
                   lds[2], lds[3], iN0, iN1, kc);

        // ---- store y_t = xG (pre-update) ----
        {
            float s0 = (q == 0) ? xg[0] : (q == 1) ? xg[2] : (q == 2) ? xg[4] : xg[6];
            float s1 = (q == 0) ? xg[1] : (q == 1) ? xg[3] : (q == 2) ? xg[5] : xg[7];
            float2 st = { s0, s1 };
            *(float2*)(ob + t * 8 + 2 * q) = st;
        }

        // ---- state update ----
#pragma unroll
        for (int c = 0; c < 8; ++c) {
            ks[c] += kc[c];
            xg[c] = fmaf(0.0016666667f, ks[c], xg[c]);   // DELTA/6
        }
#pragma unroll
        for (int i = 0; i < 16; ++i) p[i] = ps[i];
        up[0] = up[1]; up[1] = up[2]; up[2] = up[3];
        { H2I u; u.i = upair_i; up[3] = u.h; }

        uu = uun;
    }
}

extern "C" void kernel_launch(void* const* d_in, const int* in_sizes, int n_in,
                              void* d_out, int out_size, void* d_ws, size_t ws_size,
                              hipStream_t stream) {
    const float* useq = (const float*)d_in[0];
    const float* xGz0 = (const float*)d_in[1];
    const float* W1   = (const float*)d_in[2];
    const float* b1   = (const float*)d_in[3];
    const float* W2   = (const float*)d_in[4];
    const float* b2   = (const float*)d_in[5];
    const float* W3   = (const float*)d_in[6];
    const float* b3   = (const float*)d_in[7];
    float* out = (float*)d_out;

    // 8192 batch / 16 per group = 512 blocks of 1 wave (all channels)
    cstr_mfma1_kernel<<<dim3(512), dim3(64), 0, stream>>>(
        useq, xGz0, W1, b1, W2, b2, W3, b3, out);
}

// Round 2
// 850.839 us; speedup vs baseline: 1.3976x; 1.1500x over previous
//
#include <hip/hip_runtime.h>

// R6: transpose-free MFMA chaining via hidden-channel permutation.
// Block = 64 thr = 1 wave owning all 64 channels (4 M-tiles) of layers 1&2
// for its 16-batch group. The hidden-layer channel numbering is permuted:
// A-tile ct, tile-row rho computes physical channel
//   pi(ct,rho) = ct<2 ? 8*(rho>>2)+4*ct+(rho&3) : 32+8*(rho>>2)+4*(ct-2)+(rho&3)
// With this assignment, each lane's 16 MFMA C-outputs (channels pi(ct,4q+r))
// are exactly the 16 B-fragment inputs the SAME lane needs for the next
// layer (channels 8q..8q+7 and 32+8q..32+8q+7). The inter-layer transpose
// -> sigmoid+pack stays entirely in registers: ZERO LDS memory, no barriers.
// Consumers (W2, W3 A-frags) keep natural K-indexing since produced values
// land at k-slot == physical channel. Only remaining DS ops: 8 ds_bpermute
// per stage for the layer-3 output gather.
// sigma-folding retained: tanh(a)=1-2*sigma(2a), with -2 and 2*log2(e)
// folded into weights/biases; each activation is rcp(1+exp2(c)).
// All dot products bit-identical to R5 (same values in same k-slots).

typedef _Float16 h2_t __attribute__((ext_vector_type(2)));
typedef _Float16 h8_t __attribute__((ext_vector_type(8)));
typedef __fp16  pk2_t __attribute__((ext_vector_type(2)));
typedef float f4_t __attribute__((ext_vector_type(4)));

union H8 { h8_t v; h2_t h[4]; int i[4]; int4 i4; };
union H2I { h2_t h; pk2_t p; int i; float _f; };

#define DEVI __device__ __forceinline__

DEVI float rcp_f(float x) { return __builtin_amdgcn_rcpf(x); }
#if __has_builtin(__builtin_amdgcn_exp2f)
DEVI float exp2_f(float x) { return __builtin_amdgcn_exp2f(x); }
#else
DEVI float exp2_f(float x) { return __expf(x * 0.69314718056f); }
#endif
DEVI int pkrtz_i(float a, float b) { H2I u; u.p = __builtin_amdgcn_cvt_pkrtz(a, b); return u.i; }
DEVI h2_t pkrtz(float a, float b)  { H2I u; u.p = __builtin_amdgcn_cvt_pkrtz(a, b); return u.h; }
DEVI int bperm(int addr, int src) { return __builtin_amdgcn_ds_bpermute(addr, src); }
DEVI int h2i(h2_t h) { H2I u; u.h = h; return u.i; }

DEVI f4_t mfma16(h8_t a, h8_t b, f4_t c) {
    return __builtin_amdgcn_mfma_f32_16x16x32_f16(a, b, c, 0, 0, 0);
}

DEVI int qsel(int q, int a, int b, int c, int d) {
    int x = (q == 0) ? a : b;
    int y = (q == 2) ? c : d;
    return (q < 2) ? x : y;
}

// hidden-channel permutation: physical channel computed at A-tile ct, row rho
DEVI int chan_of(int ct, int rho) {
    int qr = rho >> 2, rr = rho & 3;
    return (ct < 2) ? (8 * qr + 4 * ct + rr)
                    : (32 + 8 * qr + 4 * (ct - 2) + rr);
}

// grey-box CSTR+flash RHS, scaled coords, per-lane (batch = lane&15)
DEVI void fg_eval(const float x[8], float F, float D, float kfg[8]) {
    float Hr  = fmaf(x[0], 0.3f, 0.7f);
    float CAr = fmaf(x[1], 0.2f, 0.5f);
    float CBr = fmaf(x[2], 0.2f, 0.5f);
    float Tr  = fmaf(x[3], 5.0f, 310.0f);
    float Hb  = fmaf(x[4], 0.3f, 0.7f);
    float CAb = fmaf(x[5], 0.2f, 0.5f);
    float CBb = fmaf(x[6], 0.2f, 0.5f);
    float Tb  = fmaf(x[7], 5.0f, 310.0f);

    float aA = 3.5f * CAb, aB = 1.1f * CBb;
    float rden = rcp_f(aA + aB);
    float CAd = aA * rden, CBd = aB * rden;
    float Fr = __builtin_amdgcn_sqrtf(Hr);
    float Fb = __builtin_amdgcn_sqrtf(Hb);
    float rTr = rcp_f(Tr);
    float k1v = 20000.0f * __expf(-3000.0f * rTr);
    float r1 = k1v * CAr;
    float rHr = rcp_f(Hr), rHb = rcp_f(Hb);

    float dHr  = F + D - Fr;
    float dCAr = (F * (1.0f - CAr) + D * (CAd - CAr)) * rHr - r1;
    float dCBr = (D * (CBd - CBr) - F * CBr) * rHr + r1;
    float dTr  = (F * (320.0f - Tr) + D * (310.0f - Tr)) * rHr
               - (40.0f / 3.0f) * rHr + (2.0f / 3.0f) * r1;
    float dHb  = Fr - Fb - D;
    float dCAb = (Fr * (CAr - CAb) + D * (CAb - CAd)) * rHb;
    float dCBb = (Fr * (CBr - CBb) + D * (CBb - CBd)) * rHb;
    float dTb  = Fr * (Tr - Tb) * rHb + (40.0f / 3.0f) * rHb;

    kfg[0] = dHr  * (10.0f / 3.0f);
    kfg[1] = dCAr * 5.0f;
    kfg[2] = dCBr * 5.0f;
    kfg[3] = dTr  * 0.2f;
    kfg[4] = dHb  * (10.0f / 3.0f);
    kfg[5] = dCAb * 5.0f;
    kfg[6] = dCBb * 5.0f;
    kfg[7] = dTb  * 0.2f;
}

struct Weights {
    h8_t a1[4][2], a2[4][2], a3[2];
    f4_t b1f[4], b2f[4], b3f;
};

DEVI int sigpair(float a, float b) {
    float s0 = rcp_f(1.0f + exp2_f(a));
    float s1 = rcp_f(1.0f + exp2_f(b));
    return pkrtz_i(s0, s1);
}

// sigma transition, fully register-local thanks to the pi channel assignment:
// acc[ct][r] holds channel pi(ct,4q+r); B-frag slot j of frag f needs channel
// 32f + 8q + j. pi makes these coincide: frag0 slots = (ct0 r0..r3, ct1
// r0..r3), frag1 slots = (ct2, ct3).
DEVI void transition_local(const f4_t a[4], H8& g0, H8& g1) {
    g0.i[0] = sigpair(a[0][0], a[0][1]);
    g0.i[1] = sigpair(a[0][2], a[0][3]);
    g0.i[2] = sigpair(a[1][0], a[1][1]);
    g0.i[3] = sigpair(a[1][2], a[1][3]);
    g1.i[0] = sigpair(a[2][0], a[2][1]);
    g1.i[1] = sigpair(a[2][2], a[2][3]);
    g1.i[2] = sigpair(a[3][0], a[3][1]);
    g1.i[3] = sigpair(a[3][2], a[3][3]);
}

// one RK slope: k = fg(x,u) + fnn([x, zvariant, u])
DEVI void eval_stage(const float x[8], const h2_t yv[16], const h2_t up[4],
                     int upair_i, float F, float D, const Weights& W,
                     int q, int iN0, int iN1, float k[8]) {
    // ---- build B1 frags: in = [x(8), ypart(32), upseq(8), u(2), pad] ----
    H8 f0, f1;
#pragma unroll
    for (int i = 0; i < 4; ++i) {
        int pxi = pkrtz_i(x[2 * i], x[2 * i + 1]);
        f0.i[i] = qsel(q, pxi, h2i(yv[i]), h2i(yv[4 + i]), h2i(yv[8 + i]));
        f1.i[i] = qsel(q, h2i(yv[12 + i]), h2i(up[i]),
                       (i == 0) ? upair_i : 0, 0);
    }

    // ---- layer 1 (all 4 M-tiles, pi-permuted channels) ----
    f4_t a[4];
#pragma unroll
    for (int ct = 0; ct < 4; ++ct) {
        a[ct] = mfma16(W.a1[ct][0], f0.v, W.b1f[ct]);
        a[ct] = mfma16(W.a1[ct][1], f1.v, a[ct]);
    }
    H8 g0, g1;
    transition_local(a, g0, g1);

    // ---- layer 2 ----
#pragma unroll
    for (int ct = 0; ct < 4; ++ct) {
        a[ct] = mfma16(W.a2[ct][0], g0.v, W.b2f[ct]);
        a[ct] = mfma16(W.a2[ct][1], g1.v, a[ct]);
    }
    transition_local(a, g0, g1);

    // ---- layer 3 (full K; output channels natural 0..7) ----
    f4_t a3 = mfma16(W.a3[0], g0.v, W.b3f);
    a3 = mfma16(W.a3[1], g1.v, a3);

    // gather nn[c] to every lane (batch = lane&15)
    float nn[8];
#pragma unroll
    for (int c = 0; c < 8; ++c) {
        int idx = (c < 4) ? iN0 : iN1;
        nn[c] = __int_as_float(bperm(idx, __float_as_int(a3[c & 3])));
    }

    float kfg[8];
    fg_eval(x, F, D, kfg);
#pragma unroll
    for (int c = 0; c < 8; ++c) k[c] = kfg[c] + nn[c];
}

__global__ __launch_bounds__(64, 1)
void cstr_mfma1_kernel(const float* __restrict__ useq, const float* __restrict__ xGz0,
                       const float* __restrict__ W1, const float* __restrict__ b1,
                       const float* __restrict__ W2, const float* __restrict__ b2,
                       const float* __restrict__ W3, const float* __restrict__ b3,
                       float* __restrict__ out)
{
    const int lane = threadIdx.x & 63;
    const int m16 = lane & 15, q = lane >> 4;
    const int b0 = blockIdx.x * 16;

    const int iN0 = m16 << 2;
    const int iN1 = (m16 + 16) << 2;

    const float S1 = 2.0f * 1.4426950408889634f;   // 2*log2(e)

    // ---- preload weights (sigma-folded, pi-permuted output columns) ----
    Weights W;
#pragma unroll
    for (int ct = 0; ct < 4; ++ct) {
        const int n = chan_of(ct, m16);            // A-frag row m16 -> channel
#pragma unroll
        for (int kh = 0; kh < 2; ++kh) {
            H8 w1f, w2f;
#pragma unroll
            for (int j = 0; j < 8; ++j) {
                int k = 32 * kh + 8 * q + j;
                float v1 = (k < 50) ? S1 * W1[k * 64 + n] : 0.0f;
                float v2 = -2.0f * S1 * W2[k * 64 + n];
                ((_Float16*)&w1f)[j] = (_Float16)v1;
                ((_Float16*)&w2f)[j] = (_Float16)v2;
            }
            W.a1[ct][kh] = w1f.v;
            W.a2[ct][kh] = w2f.v;
        }
        f4_t bb1, bb2;
#pragma unroll
        for (int r = 0; r < 4; ++r) {
            int ch = chan_of(ct, 4 * q + r);       // C slot (ct,q,r) -> channel
            bb1[r] = S1 * b1[ch];
            float cs = 0.0f;
            for (int j = 0; j < 64; ++j) cs += W2[j * 64 + ch];
            bb2[r] = S1 * (b2[ch] + cs);
        }
        W.b1f[ct] = bb1;
        W.b2f[ct] = bb2;
    }
#pragma unroll
    for (int kh = 0; kh < 2; ++kh) {
        H8 w3f;
#pragma unroll
        for (int j = 0; j < 8; ++j) {
            int k = 32 * kh + 8 * q + j;
            ((_Float16*)&w3f)[j] = (m16 < 8) ? (_Float16)(-2.0f * W3[k * 8 + m16])
                                             : (_Float16)0.0f;
        }
        W.a3[kh] = w3f.v;
    }
    {
        f4_t bb3;
#pragma unroll
        for (int r = 0; r < 4; ++r) {
            int c = 4 * q + r;
            float v = 0.0f;
            if (c < 8) {
                float cs = 0.0f;
                for (int j = 0; j < 64; ++j) cs += W3[j * 8 + c];
                v = b3[c] + cs;
            }
            bb3[r] = v;
        }
        W.b3f = bb3;
    }

    // ---- per-batch state (batch = lane&15; replicated across quads) ----
    const float* xz = xGz0 + (size_t)(b0 + m16) * 48;
    float xg[8];
#pragma unroll
    for (int c = 0; c < 8; ++c) xg[c] = xz[c];
    h2_t p[16];
#pragma unroll
    for (int i = 0; i < 16; ++i) p[i] = pkrtz(xz[8 + 2 * i], xz[9 + 2 * i]);
    h2_t up[4];
#pragma unroll
    for (int i = 0; i < 4; ++i) up[i] = pkrtz(xz[40 + 2 * i], xz[41 + 2 * i]);

    const float* ub = useq + (size_t)(b0 + m16) * 512;
    float* ob = out + (size_t)(b0 + m16) * 2048;

    float kc[8], ks[8], xv[8];

    float2 uu = *(const float2*)(ub);       // u for t=0

#pragma unroll 1
    for (int t = 0; t < 256; ++t) {
        // prefetch next step's u (wraps harmlessly at t=255)
        const float2 uun = *(const float2*)(ub + ((2 * t + 2) & 511));

        const float u0 = uu.x, u1 = uu.y;
        const float F = fmaf(u0, 0.1f, 1.0f);
        const float D = fmaf(u1, 0.05f, 0.5f);
        const int upair_i = pkrtz_i(u0, u1);

        // ycat pairs = [ypseq(16 pairs), xG(4 pairs)]
        h2_t pc[20];
#pragma unroll
        for (int i = 0; i < 16; ++i) pc[i] = p[i];
#pragma unroll
        for (int i = 0; i < 4; ++i) pc[16 + i] = pkrtz(xg[2 * i], xg[2 * i + 1]);
        h2_t pi[16], ps[16];
        const h2_t half2c = { (_Float16)0.5f, (_Float16)0.5f };
#pragma unroll
        for (int i = 0; i < 16; ++i) {
            pi[i] = (pc[i] + pc[i + 4]) * half2c;
            ps[i] = pc[i + 4];
        }

        // ---- RK4 (all register-local; no LDS memory, no barriers) ----
        eval_stage(xg, p,  up, upair_i, F, D, W, q, iN0, iN1, kc);
#pragma unroll
        for (int c = 0; c < 8; ++c) { ks[c] = kc[c]; xv[c] = fmaf(0.005f, kc[c], xg[c]); }
        eval_stage(xv, pi, up, upair_i, F, D, W, q, iN0, iN1, kc);
#pragma unroll
        for (int c = 0; c < 8; ++c) { ks[c] = fmaf(2.0f, kc[c], ks[c]); xv[c] = fmaf(0.005f, kc[c], xg[c]); }
        eval_stage(xv, pi, up, upair_i, F, D, W, q, iN0, iN1, kc);
#pragma unroll
        for (int c = 0; c < 8; ++c) { ks[c] = fmaf(2.0f, kc[c], ks[c]); xv[c] = fmaf(0.01f, kc[c], xg[c]); }
        eval_stage(xv, ps, up, upair_i, F, D, W, q, iN0, iN1, kc);

        // ---- store y_t = xG (pre-update) ----
        {
            float s0 = (q == 0) ? xg[0] : (q == 1) ? xg[2] : (q == 2) ? xg[4] : xg[6];
            float s1 = (q == 0) ? xg[1] : (q == 1) ? xg[3] : (q == 2) ? xg[5] : xg[7];
            float2 st = { s0, s1 };
            *(float2*)(ob + t * 8 + 2 * q) = st;
        }

        // ---- state update ----
#pragma unroll
        for (int c = 0; c < 8; ++c) {
            ks[c] += kc[c];
            xg[c] = fmaf(0.0016666667f, ks[c], xg[c]);   // DELTA/6
        }
#pragma unroll
        for (int i = 0; i < 16; ++i) p[i] = ps[i];
        up[0] = up[1]; up[1] = up[2]; up[2] = up[3];
        { H2I u; u.i = upair_i; up[3] = u.h; }

        uu = uun;
    }
}

extern "C" void kernel_launch(void* const* d_in, const int* in_sizes, int n_in,
                              void* d_out, int out_size, void* d_ws, size_t ws_size,
                              hipStream_t stream) {
    const float* useq = (const float*)d_in[0];
    const float* xGz0 = (const float*)d_in[1];
    const float* W1   = (const float*)d_in[2];
    const float* b1   = (const float*)d_in[3];
    const float* W2   = (const float*)d_in[4];
    const float* b2   = (const float*)d_in[5];
    const float* W3   = (const float*)d_in[6];
    const float* b3   = (const float*)d_in[7];
    float* out = (float*)d_out;

    // 8192 batch / 16 per group = 512 blocks of 1 wave (all channels)
    cstr_mfma1_kernel<<<dim3(512), dim3(64), 0, stream>>>(
        useq, xGz0, W1, b1, W2, b2, W3, b3, out);
}